// Round 10
// baseline (2579.261 us; speedup 1.0000x reference)
//
#include <hip/hip_runtime.h>

#define NT 256   // 4 waves; wave w owns gate-tiles 4w..4w+3 (units 16w..16w+15); 4 samples/block

typedef _Float16 f16x8 __attribute__((ext_vector_type(8)));
typedef float    f32x4 __attribute__((ext_vector_type(4)));

#define MFMA(a, b, c) __builtin_amdgcn_mfma_f32_16x16x32_f16((a), (b), (c), 0, 0, 0)

#if __has_builtin(__builtin_amdgcn_exp2f)
__device__ __forceinline__ float fexp(float x) { return __builtin_amdgcn_exp2f(x * 1.4426950408889634f); }
#else
__device__ __forceinline__ float fexp(float x) { return __expf(x); }
#endif
#if __has_builtin(__builtin_amdgcn_rcpf)
__device__ __forceinline__ float frcp(float x) { return __builtin_amdgcn_rcpf(x); }
#else
__device__ __forceinline__ float frcp(float x) { return 1.0f / x; }
#endif
__device__ __forceinline__ float sigm(float x)  { return frcp(1.0f + fexp(-x)); }
__device__ __forceinline__ float tanh_(float x) { return 1.0f - 2.0f * frcp(1.0f + fexp(2.0f * x)); }
__device__ __forceinline__ float lrelu(float x) { return x > 0.0f ? x : 0.01f * x; }

__device__ __forceinline__ f16x8 ld8(const float* p) {
    const float4* q = (const float4*)p;
    float4 a = q[0], b = q[1];
    f16x8 r = { (_Float16)a.x, (_Float16)a.y, (_Float16)a.z, (_Float16)a.w,
                (_Float16)b.x, (_Float16)b.y, (_Float16)b.z, (_Float16)b.w };
    return r;
}
__device__ __forceinline__ unsigned pack2(float a, float b) {
    union { _Float16 h[2]; unsigned u; } x;
    x.h[0] = (_Float16)a; x.h[1] = (_Float16)b; return x.u;
}
__device__ __forceinline__ _Float16 half_of(unsigned v, int sel) {
    union { unsigned u; _Float16 h[2]; } x; x.u = v; return x.h[sel];
}

__global__ __launch_bounds__(NT, 2)
void gen_kernel(
    const float* __restrict__ noise,
    const float* __restrict__ w_ih0, const float* __restrict__ w_hh0,
    const float* __restrict__ b_ih0, const float* __restrict__ b_hh0,
    const float* __restrict__ w_ih1, const float* __restrict__ w_hh1,
    const float* __restrict__ b_ih1, const float* __restrict__ b_hh1,
    const float* __restrict__ w_ih2, const float* __restrict__ w_hh2,
    const float* __restrict__ b_ih2, const float* __restrict__ b_hh2,
    const float* __restrict__ fc1_w, const float* __restrict__ fc1_b,
    const float* __restrict__ fc2_w, const float* __restrict__ fc2_b,
    const float* __restrict__ fc3_w, const float* __restrict__ fc3_b,
    const int*   __restrict__ flow_len_p,
    float* __restrict__ out)
{
    // h-state per layer, double-buffered, [sample-col][unit], 72-half rows
    __shared__ _Float16 sh[3][2][16][72] __attribute__((aligned(16)));   // 13.8 KB

    const int tid  = threadIdx.x;
    const int l    = tid & 63;
    const int w    = tid >> 6;     // wave 0..3
    const int ls   = l & 15;       // sample col (B/C) == row-in-tile (A)
    const int lj   = l >> 4;       // k-group / C row-group
    const int base = blockIdx.x * 4;
    const int T    = flow_len_p[0];

    // ---------- stationary fragments ----------
    // Gate-interleaved row space: tile Tg row rt -> orig row (rt&3)*64 + 4*Tg + (rt>>2)
    f16x8 A1[4][4], A2[4][4], A0[4][3];
    float b1v[4][4], b2v[4][4];
    int   uc[4];
#pragma unroll
    for (int tt = 0; tt < 4; ++tt) {
        const int r = (ls & 3) * 64 + 4 * (4 * w + tt) + (ls >> 2);
#pragma unroll
        for (int kc = 0; kc < 2; ++kc) {
            A1[tt][kc]     = ld8(w_ih1 + r * 64 + 32 * kc + 8 * lj);
            A1[tt][2 + kc] = ld8(w_hh1 + r * 64 + 32 * kc + 8 * lj);
            A2[tt][kc]     = ld8(w_ih2 + r * 64 + 32 * kc + 8 * lj);
            A2[tt][2 + kc] = ld8(w_hh2 + r * 64 + 32 * kc + 8 * lj);
            A0[tt][kc]     = ld8(w_hh0 + r * 64 + 32 * kc + 8 * lj);
        }
        {   // layer0 x-chunk: k<3 = w_ih0, k==3 = combined bias, else 0
            f16x8 v;
#pragma unroll
            for (int i = 0; i < 8; ++i) {
                int kl = 8 * lj + i;
                float x = (kl < 3) ? w_ih0[r * 3 + kl]
                        : (kl == 3) ? (b_ih0[r] + b_hh0[r]) : 0.0f;
                v[i] = (_Float16)x;
            }
            A0[tt][2] = v;
        }
        const int u = 16 * w + 4 * tt + lj;   // C-side unit for this tile
        uc[tt] = u;
#pragma unroll
        for (int g = 0; g < 4; ++g) {
            b1v[tt][g] = b_ih1[g * 64 + u] + b_hh1[g * 64 + u];
            b2v[tt][g] = b_ih2[g * 64 + u] + b_hh2[g * 64 + u];
        }
    }
    // head fragments (every wave: redundant head)
    f16x8 F1[2][2], F2, F3;
#pragma unroll
    for (int tt = 0; tt < 2; ++tt)
#pragma unroll
        for (int kc = 0; kc < 2; ++kc)
            F1[tt][kc] = ld8(fc1_w + (16 * tt + ls) * 64 + 32 * kc + 8 * lj);
    F2 = ld8(fc2_w + ls * 32 + 8 * lj);
    {
        f16x8 v;
#pragma unroll
        for (int i = 0; i < 8; ++i) {
            int k = 8 * lj + i;
            v[i] = (_Float16)((ls < 3 && k < 16) ? fc3_w[ls * 16 + k] : 0.0f);
        }
        F3 = v;
    }
    float hb1a[4], hb1b[4], hb2r[4];
#pragma unroll
    for (int r = 0; r < 4; ++r) {
        hb1a[r] = fc1_b[4 * lj + r];
        hb1b[r] = fc1_b[16 + 4 * lj + r];
        hb2r[r] = fc2_b[4 * lj + r];
    }
    const float fb3_0 = fc3_b[0], fb3_1 = fc3_b[1], fb3_2 = fc3_b[2];

    // ---------- init ----------
    for (int i = tid; i < 3 * 2 * 16 * 72; i += NT) ((_Float16*)sh)[i] = (_Float16)0.0f;
    __syncthreads();

    float c0[4] = {0,0,0,0}, c1[4] = {0,0,0,0}, c2[4] = {0,0,0,0};
    const float zb[4] = {0, 0, 0, 0};

#define RD(L, p, kb) (*(const f16x8*)&sh[L][p][ls][(kb) + 8 * lj])

#define ACT(a, bv, cref, L, p, u) {                                            \
        float gi = a[0] + bv[0], gf = a[1] + bv[1];                            \
        float gg = a[2] + bv[2], go = a[3] + bv[3];                            \
        cref = sigm(gf) * cref + sigm(gi) * tanh_(gg);                         \
        sh[L][p][ls][u] = (_Float16)(sigm(go) * tanh_(cref)); }

    // ---------- prologue: h0(0) = ACT0(Wi0·[noise;1]) into buffer 0 ----------
    {
        f16x8 bx;
#pragma unroll
        for (int i = 0; i < 8; ++i) bx[i] = (_Float16)0.0f;
        if (lj == 0) {
            if (ls < 4) {
                bx[0] = (_Float16)noise[(base + ls) * 3 + 0];
                bx[1] = (_Float16)noise[(base + ls) * 3 + 1];
                bx[2] = (_Float16)noise[(base + ls) * 3 + 2];
            }
            bx[3] = (_Float16)1.0f;
        }
#pragma unroll
        for (int tt = 0; tt < 4; ++tt) {
            f32x4 a = {0, 0, 0, 0};
            a = MFMA(A0[tt][2], bx, a);
            ACT(a, zb, c0[tt], 0, 0, uc[tt])
        }
    }
    __syncthreads();

    // ---------- time loop: 3 barriers/step ----------
    for (int t = 0; t < T; ++t) {
        const int pc = t & 1, pp = pc ^ 1;
        // P1: gates1 = [Wi1|Wh1]·[h0(pc); h1(pp)] -> ACT1 -> h1(pc)
        {
            f16x8 q0 = RD(0, pc, 0), q1 = RD(0, pc, 32);
            f16x8 q2 = RD(1, pp, 0), q3 = RD(1, pp, 32);
#pragma unroll
            for (int tt = 0; tt < 4; ++tt) {
                f32x4 a = {0, 0, 0, 0};
                a = MFMA(A1[tt][0], q0, a); a = MFMA(A1[tt][1], q1, a);
                a = MFMA(A1[tt][2], q2, a); a = MFMA(A1[tt][3], q3, a);
                ACT(a, b1v[tt], c1[tt], 1, pc, uc[tt])
            }
        }
        __syncthreads();
        // P2: gates2 = [Wi2|Wh2]·[h1(pc); h2(pp)] -> ACT2 -> h2(pc)
        {
            f16x8 q0 = RD(1, pc, 0), q1 = RD(1, pc, 32);
            f16x8 q2 = RD(2, pp, 0), q3 = RD(2, pp, 32);
#pragma unroll
            for (int tt = 0; tt < 4; ++tt) {
                f32x4 a = {0, 0, 0, 0};
                a = MFMA(A2[tt][0], q0, a); a = MFMA(A2[tt][1], q1, a);
                a = MFMA(A2[tt][2], q2, a); a = MFMA(A2[tt][3], q3, a);
                ACT(a, b2v[tt], c2[tt], 2, pc, uc[tt])
            }
        }
        __syncthreads();
        // P3: redundant head (all waves) + layer0 -> h0(pp).  y3 closes the
        // recurrence IN-REGISTER: fc3's C puts y3[0..2](col ls) in lane (ls,lj=0),
        // exactly the lane whose A0 x-fragment consumes it (k-slots 0..3).
        {
            f16x8 e0 = RD(2, pc, 0), e1 = RD(2, pc, 32);
            f32x4 y1a = {0, 0, 0, 0}, y1b = {0, 0, 0, 0};
            y1a = MFMA(F1[0][0], e0, y1a); y1a = MFMA(F1[0][1], e1, y1a);
            y1b = MFMA(F1[1][0], e0, y1b); y1b = MFMA(F1[1][1], e1, y1b);
            unsigned pk[4];
#pragma unroll
            for (int r = 0; r < 4; ++r)
                pk[r] = pack2(lrelu(y1a[r] + hb1a[r]), lrelu(y1b[r] + hb1b[r]));
            const int laneA = ls + 32 * (lj & 1);
            const int sel   = lj >> 1;
            f16x8 by1;
#pragma unroll
            for (int i = 0; i < 4; ++i) {
                unsigned v = (unsigned)__shfl((int)pk[i], laneA);
                by1[i] = half_of(v, sel);
            }
#pragma unroll
            for (int i = 0; i < 4; ++i) {
                unsigned v = (unsigned)__shfl((int)pk[i], laneA + 16);
                by1[4 + i] = half_of(v, sel);
            }
            f32x4 y2 = {0, 0, 0, 0};
            y2 = MFMA(F2, by1, y2);
            float y2r[4];
#pragma unroll
            for (int r = 0; r < 4; ++r) y2r[r] = lrelu(y2[r] + hb2r[r]);
            f16x8 by2;
#pragma unroll
            for (int i = 0; i < 4; ++i) {
                float v = __shfl(y2r[i], laneA);
                by2[i] = (lj < 2) ? (_Float16)v : (_Float16)0.0f;
            }
#pragma unroll
            for (int i = 0; i < 4; ++i) {
                float v = __shfl(y2r[i], laneA + 16);
                by2[4 + i] = (lj < 2) ? (_Float16)v : (_Float16)0.0f;
            }
            f32x4 y3 = {0, 0, 0, 0};
            y3 = MFMA(F3, by2, y3);
            f16x8 bx;
#pragma unroll
            for (int i = 0; i < 8; ++i) bx[i] = (_Float16)0.0f;
            float o0 = 0.0f, o1 = 0.0f, o2 = 0.0f;
            if (lj == 0) {
                o0 = lrelu(y3[0] + fb3_0);
                o1 = lrelu(y3[1] + fb3_1);
                o2 = lrelu(y3[2] + fb3_2);
                bx[0] = (_Float16)o0; bx[1] = (_Float16)o1;
                bx[2] = (_Float16)o2; bx[3] = (_Float16)1.0f;
            }
            if (w == 0 && lj == 0 && ls < 4) {
                float* op = out + ((size_t)(base + ls) * T + t) * 3;
                op[0] = o0; op[1] = o1; op[2] = o2;
            }
            // layer0: gates0 = Wh0·h0(pc) + Wi0p·[y3;1] -> ACT0 -> h0(pp)
            f16x8 g0 = RD(0, pc, 0), g1 = RD(0, pc, 32);
#pragma unroll
            for (int tt = 0; tt < 4; ++tt) {
                f32x4 a = {0, 0, 0, 0};
                a = MFMA(A0[tt][0], g0, a);
                a = MFMA(A0[tt][1], g1, a);
                a = MFMA(A0[tt][2], bx, a);
                ACT(a, zb, c0[tt], 0, pp, uc[tt])
            }
        }
        __syncthreads();
    }
}

extern "C" void kernel_launch(void* const* d_in, const int* in_sizes, int n_in,
                              void* d_out, int out_size, void* d_ws, size_t ws_size,
                              hipStream_t stream) {
    const float* noise = (const float*)d_in[0];
    const float* w_ih0 = (const float*)d_in[1];
    const float* w_hh0 = (const float*)d_in[2];
    const float* b_ih0 = (const float*)d_in[3];
    const float* b_hh0 = (const float*)d_in[4];
    const float* w_ih1 = (const float*)d_in[5];
    const float* w_hh1 = (const float*)d_in[6];
    const float* b_ih1 = (const float*)d_in[7];
    const float* b_hh1 = (const float*)d_in[8];
    const float* w_ih2 = (const float*)d_in[9];
    const float* w_hh2 = (const float*)d_in[10];
    const float* b_ih2 = (const float*)d_in[11];
    const float* b_hh2 = (const float*)d_in[12];
    const float* fc1w  = (const float*)d_in[13];
    const float* fc1b  = (const float*)d_in[14];
    const float* fc2w  = (const float*)d_in[15];
    const float* fc2b  = (const float*)d_in[16];
    const float* fc3w  = (const float*)d_in[17];
    const float* fc3b  = (const float*)d_in[18];
    const int*   flp   = (const int*)d_in[19];

    gen_kernel<<<dim3(512), dim3(NT), 0, stream>>>(
        noise, w_ih0, w_hh0, b_ih0, b_hh0,
        w_ih1, w_hh1, b_ih1, b_hh1,
        w_ih2, w_hh2, b_ih2, b_hh2,
        fc1w, fc1b, fc2w, fc2b, fc3w, fc3b,
        flp, (float*)d_out);
}

// Round 11
// 950.807 us; speedup vs baseline: 2.7127x; 2.7127x over previous
//
#include <hip/hip_runtime.h>

#define NT 512   // 8 waves; wave w owns gate-tiles {2w,2w+1} = units 8w..8w+7 (all 4 gates)

typedef _Float16 f16x8 __attribute__((ext_vector_type(8)));
typedef _Float16 f16x4 __attribute__((ext_vector_type(4)));
typedef float    f32x4 __attribute__((ext_vector_type(4)));

#define MFMA(a, b, c) __builtin_amdgcn_mfma_f32_16x16x32_f16((a), (b), (c), 0, 0, 0)

#if __has_builtin(__builtin_amdgcn_exp2f)
__device__ __forceinline__ float fexp(float x) { return __builtin_amdgcn_exp2f(x * 1.4426950408889634f); }
#else
__device__ __forceinline__ float fexp(float x) { return __expf(x); }
#endif
#if __has_builtin(__builtin_amdgcn_rcpf)
__device__ __forceinline__ float frcp(float x) { return __builtin_amdgcn_rcpf(x); }
#else
__device__ __forceinline__ float frcp(float x) { return 1.0f / x; }
#endif
__device__ __forceinline__ float sigm(float x)  { return frcp(1.0f + fexp(-x)); }
__device__ __forceinline__ float tanh_(float x) { return 1.0f - 2.0f * frcp(1.0f + fexp(2.0f * x)); }
__device__ __forceinline__ float lrelu(float x) { return x > 0.0f ? x : 0.01f * x; }

__device__ __forceinline__ f16x8 ld8(const float* p) {
    const float4* q = (const float4*)p;
    float4 a = q[0], b = q[1];
    f16x8 r = { (_Float16)a.x, (_Float16)a.y, (_Float16)a.z, (_Float16)a.w,
                (_Float16)b.x, (_Float16)b.y, (_Float16)b.z, (_Float16)b.w };
    return r;
}

__global__ __launch_bounds__(NT, 2)
void gen_kernel(
    const float* __restrict__ noise,
    const float* __restrict__ w_ih0, const float* __restrict__ w_hh0,
    const float* __restrict__ b_ih0, const float* __restrict__ b_hh0,
    const float* __restrict__ w_ih1, const float* __restrict__ w_hh1,
    const float* __restrict__ b_ih1, const float* __restrict__ b_hh1,
    const float* __restrict__ w_ih2, const float* __restrict__ w_hh2,
    const float* __restrict__ b_ih2, const float* __restrict__ b_hh2,
    const float* __restrict__ fc1_w, const float* __restrict__ fc1_b,
    const float* __restrict__ fc2_w, const float* __restrict__ fc2_b,
    const float* __restrict__ fc3_w, const float* __restrict__ fc3_b,
    const int*   __restrict__ flow_len_p,
    float* __restrict__ out)
{
    // h-state: [layer][buf][col*64 + rotated unit position], pitch 64 halves.
    // k-group kg (8 units) of column ls is stored at slot (kg+ls)&7 — spreads
    // b128 start banks across all 32 banks (R9's +72 pad gave 8 starts -> 4-way).
    __shared__ _Float16 sh[3][2][16 * 64] __attribute__((aligned(16)));  // 12 KB
    __shared__ _Float16 sx [16][40] __attribute__((aligned(16)));  // x: [0..2]=y3, [3]=1, rest 0
    __shared__ _Float16 sy1[16][40] __attribute__((aligned(16)));
    __shared__ _Float16 sy2[16][40] __attribute__((aligned(16)));

    const int tid  = threadIdx.x;
    const int l    = tid & 63;
    const int w    = tid >> 6;     // wave 0..7
    const int ls   = l & 15;       // sample col (B/C) == row-in-tile (A)
    const int lj   = l >> 4;       // k-group / C row-group
    const int base = blockIdx.x * 8;
    const int T    = flow_len_p[0];

    // ---------- A fragments (weights, fp16, register/AGPR-stationary) ----------
    const int gA  = ls & 3;
    const int rA0 = gA * 64 + 4 * (2 * w + 0) + (ls >> 2);
    const int rA1 = gA * 64 + 4 * (2 * w + 1) + (ls >> 2);

    f16x8 A1[2][4], A2[2][4], A0[2][3];
#pragma unroll
    for (int kc = 0; kc < 2; ++kc) {
        A1[0][kc]     = ld8(w_ih1 + rA0 * 64 + 32 * kc + 8 * lj);
        A1[1][kc]     = ld8(w_ih1 + rA1 * 64 + 32 * kc + 8 * lj);
        A1[0][2 + kc] = ld8(w_hh1 + rA0 * 64 + 32 * kc + 8 * lj);
        A1[1][2 + kc] = ld8(w_hh1 + rA1 * 64 + 32 * kc + 8 * lj);
        A2[0][kc]     = ld8(w_ih2 + rA0 * 64 + 32 * kc + 8 * lj);
        A2[1][kc]     = ld8(w_ih2 + rA1 * 64 + 32 * kc + 8 * lj);
        A2[0][2 + kc] = ld8(w_hh2 + rA0 * 64 + 32 * kc + 8 * lj);
        A2[1][2 + kc] = ld8(w_hh2 + rA1 * 64 + 32 * kc + 8 * lj);
        A0[0][kc]     = ld8(w_hh0 + rA0 * 64 + 32 * kc + 8 * lj);
        A0[1][kc]     = ld8(w_hh0 + rA1 * 64 + 32 * kc + 8 * lj);
    }
#pragma unroll
    for (int tt = 0; tt < 2; ++tt) {
        const int r = tt ? rA1 : rA0;
        f16x8 v;
#pragma unroll
        for (int i = 0; i < 8; ++i) {
            int kl = 8 * lj + i;
            float x = (kl < 3) ? w_ih0[r * 3 + kl]
                    : (kl == 3) ? (b_ih0[r] + b_hh0[r]) : 0.0f;
            v[i] = (_Float16)x;
        }
        A0[tt][2] = v;
    }
    // head A-frags
    f16x8 F1[2][2], F2, F3;
#pragma unroll
    for (int tt = 0; tt < 2; ++tt)
#pragma unroll
        for (int kc = 0; kc < 2; ++kc)
            F1[tt][kc] = ld8(fc1_w + (16 * tt + ls) * 64 + 32 * kc + 8 * lj);
    F2 = ld8(fc2_w + ls * 32 + 8 * lj);
    {
        f16x8 v;
#pragma unroll
        for (int i = 0; i < 8; ++i) {
            int k = 8 * lj + i;
            v[i] = (_Float16)((ls < 3 && k < 16) ? fc3_w[ls * 16 + k] : 0.0f);
        }
        F3 = v;
    }
    const int uc0 = 8 * w + lj, uc1 = 8 * w + 4 + lj;
    float b1v[2][4], b2v[2][4];
#pragma unroll
    for (int g = 0; g < 4; ++g) {
        b1v[0][g] = b_ih1[g * 64 + uc0] + b_hh1[g * 64 + uc0];
        b1v[1][g] = b_ih1[g * 64 + uc1] + b_hh1[g * 64 + uc1];
        b2v[0][g] = b_ih2[g * 64 + uc0] + b_hh2[g * 64 + uc0];
        b2v[1][g] = b_ih2[g * 64 + uc1] + b_hh2[g * 64 + uc1];
    }
    float hb1a[4], hb1b[4], hb2[4];
#pragma unroll
    for (int r = 0; r < 4; ++r) {
        hb1a[r] = fc1_b[4 * lj + r];
        hb1b[r] = fc1_b[16 + 4 * lj + r];
        hb2[r]  = fc2_b[4 * lj + r];
    }
    float fb3[3] = { fc3_b[0], fc3_b[1], fc3_b[2] };

    // ---------- LDS init ----------
    for (int i = tid; i < 3 * 2 * 16 * 64; i += NT) ((_Float16*)sh)[i] = (_Float16)0.0f;
    for (int i = tid; i < 16 * 40; i += NT) {
        ((_Float16*)sx)[i]  = (_Float16)0.0f;
        ((_Float16*)sy1)[i] = (_Float16)0.0f;
        ((_Float16*)sy2)[i] = (_Float16)0.0f;
    }
    __syncthreads();
    if (tid < 16) sx[tid][3] = (_Float16)1.0f;
    if (tid < 24) {
        int s = tid / 3, d = tid % 3;
        sx[s][d] = (_Float16)noise[(base + s) * 3 + d];
    }

    float c0[2] = {0, 0}, c1[2] = {0, 0}, c2[2] = {0, 0};
    __syncthreads();

    // rotated B-fragment read: logical k-group kg of column ls
#define RD(L, p, kg) (*(const f16x8*)&sh[L][p][ls * 64 + 8 * (((kg) + ls) & 7)])
    // rotated h write for (col ls, unit u)
#define HADDR(u) (ls * 64 + 8 * ((((u) >> 3) + ls) & 7) + ((u) & 7))

#define ACT(acc, bv, cref, L, p, u) {                                          \
        float gi = acc[0] + bv[0], gf = acc[1] + bv[1];                        \
        float gg = acc[2] + bv[2], go = acc[3] + bv[3];                        \
        cref = sigm(gf) * cref + sigm(gi) * tanh_(gg);                         \
        sh[L][p][HADDR(u)] = (_Float16)(sigm(go) * tanh_(cref)); }

    // ---------- prologue: h0(0) from noise (h-part is zero) ----------
    {
        f16x8 bx = *(const f16x8*)&sx[ls][8 * lj];
        f32x4 a0 = {0, 0, 0, 0}, a1 = {0, 0, 0, 0};
        a0 = MFMA(A0[0][2], bx, a0);
        a1 = MFMA(A0[1][2], bx, a1);
        float zb[4] = {0, 0, 0, 0};
        ACT(a0, zb, c0[0], 0, 0, uc0)
        ACT(a1, zb, c0[1], 0, 0, uc1)
    }
    __syncthreads();

    // ---------- time loop: 4 barriers/step ----------
    for (int t = 0; t < T; ++t) {
        const int pc = t & 1, pp = pc ^ 1;
        // I1: gates1 = [Wi1|Wh1]·[h0(pc); h1(pp)] -> ACT1 -> h1(pc)
        // r0,r1 (h0(pc) B-frags) are kept in registers for reuse in I3.
        f16x8 r0 = RD(0, pc, lj), r1 = RD(0, pc, 4 + lj);
        {
            f16x8 q2 = RD(1, pp, lj), q3 = RD(1, pp, 4 + lj);
            f32x4 a0 = {0, 0, 0, 0}, a1 = {0, 0, 0, 0};
            a0 = MFMA(A1[0][0], r0, a0); a1 = MFMA(A1[1][0], r0, a1);
            a0 = MFMA(A1[0][1], r1, a0); a1 = MFMA(A1[1][1], r1, a1);
            a0 = MFMA(A1[0][2], q2, a0); a1 = MFMA(A1[1][2], q2, a1);
            a0 = MFMA(A1[0][3], q3, a0); a1 = MFMA(A1[1][3], q3, a1);
            ACT(a0, b1v[0], c1[0], 1, pc, uc0)
            ACT(a1, b1v[1], c1[1], 1, pc, uc1)
        }
        __syncthreads();
        // I2: gates2 = [Wi2|Wh2]·[h1(pc); h2(pp)] -> ACT2 -> h2(pc)
        {
            f16x8 q0 = RD(1, pc, lj), q1 = RD(1, pc, 4 + lj);
            f16x8 q2 = RD(2, pp, lj), q3 = RD(2, pp, 4 + lj);
            f32x4 a0 = {0, 0, 0, 0}, a1 = {0, 0, 0, 0};
            a0 = MFMA(A2[0][0], q0, a0); a1 = MFMA(A2[1][0], q0, a1);
            a0 = MFMA(A2[0][1], q1, a0); a1 = MFMA(A2[1][1], q1, a1);
            a0 = MFMA(A2[0][2], q2, a0); a1 = MFMA(A2[1][2], q2, a1);
            a0 = MFMA(A2[0][3], q3, a0); a1 = MFMA(A2[1][3], q3, a1);
            ACT(a0, b2v[0], c2[0], 2, pc, uc0)
            ACT(a1, b2v[1], c2[1], 2, pc, uc1)
        }
        __syncthreads();
        // I3: layer0-hh using register-held r0,r1 (acc held to I4) || head on wave 0
        f32x4 h0a = {0, 0, 0, 0}, h0b = {0, 0, 0, 0};
        h0a = MFMA(A0[0][0], r0, h0a); h0b = MFMA(A0[1][0], r0, h0b);
        h0a = MFMA(A0[0][1], r1, h0a); h0b = MFMA(A0[1][1], r1, h0b);
        if (w == 0) {
            f16x8 bh0 = RD(2, pc, lj), bh1 = RD(2, pc, 4 + lj);
            f32x4 y1a = {0, 0, 0, 0}, y1b = {0, 0, 0, 0};
            y1a = MFMA(F1[0][0], bh0, y1a); y1b = MFMA(F1[1][0], bh0, y1b);
            y1a = MFMA(F1[0][1], bh1, y1a); y1b = MFMA(F1[1][1], bh1, y1b);
            f16x4 v;
#pragma unroll
            for (int r = 0; r < 4; ++r) v[r] = (_Float16)lrelu(y1a[r] + hb1a[r]);
            *(f16x4*)&sy1[ls][4 * lj] = v;
#pragma unroll
            for (int r = 0; r < 4; ++r) v[r] = (_Float16)lrelu(y1b[r] + hb1b[r]);
            *(f16x4*)&sy1[ls][16 + 4 * lj] = v;
            f16x8 by1 = *(const f16x8*)&sy1[ls][8 * lj];
            f32x4 y2 = {0, 0, 0, 0};
            y2 = MFMA(F2, by1, y2);
#pragma unroll
            for (int r = 0; r < 4; ++r) v[r] = (_Float16)lrelu(y2[r] + hb2[r]);
            *(f16x4*)&sy2[ls][4 * lj] = v;
            f16x8 by2 = *(const f16x8*)&sy2[ls][8 * lj];
            f32x4 y3 = {0, 0, 0, 0};
            y3 = MFMA(F3, by2, y3);
            if (lj == 0) {                       // C rows 0..3 -> d = 0..2
                float o0 = lrelu(y3[0] + fb3[0]);
                float o1 = lrelu(y3[1] + fb3[1]);
                float o2 = lrelu(y3[2] + fb3[2]);
                sx[ls][0] = (_Float16)o0;
                sx[ls][1] = (_Float16)o1;
                sx[ls][2] = (_Float16)o2;
                if (ls < 8) {
                    float* op = out + ((size_t)(base + ls) * T + t) * 3;
                    op[0] = o0; op[1] = o1; op[2] = o2;
                }
            }
        }
        __syncthreads();
        // I4: gates0 += Wi0p·[y3;1;0..] -> ACT0 -> h0(pp)
        {
            f16x8 bx = *(const f16x8*)&sx[ls][8 * lj];
            h0a = MFMA(A0[0][2], bx, h0a);
            h0b = MFMA(A0[1][2], bx, h0b);
            float zb[4] = {0, 0, 0, 0};
            ACT(h0a, zb, c0[0], 0, pp, uc0)
            ACT(h0b, zb, c0[1], 0, pp, uc1)
        }
        __syncthreads();
    }
}

extern "C" void kernel_launch(void* const* d_in, const int* in_sizes, int n_in,
                              void* d_out, int out_size, void* d_ws, size_t ws_size,
                              hipStream_t stream) {
    const float* noise = (const float*)d_in[0];
    const float* w_ih0 = (const float*)d_in[1];
    const float* w_hh0 = (const float*)d_in[2];
    const float* b_ih0 = (const float*)d_in[3];
    const float* b_hh0 = (const float*)d_in[4];
    const float* w_ih1 = (const float*)d_in[5];
    const float* w_hh1 = (const float*)d_in[6];
    const float* b_ih1 = (const float*)d_in[7];
    const float* b_hh1 = (const float*)d_in[8];
    const float* w_ih2 = (const float*)d_in[9];
    const float* w_hh2 = (const float*)d_in[10];
    const float* b_ih2 = (const float*)d_in[11];
    const float* b_hh2 = (const float*)d_in[12];
    const float* fc1w  = (const float*)d_in[13];
    const float* fc1b  = (const float*)d_in[14];
    const float* fc2w  = (const float*)d_in[15];
    const float* fc2b  = (const float*)d_in[16];
    const float* fc3w  = (const float*)d_in[17];
    const float* fc3b  = (const float*)d_in[18];
    const int*   flp   = (const int*)d_in[19];

    gen_kernel<<<dim3(256), dim3(NT), 0, stream>>>(
        noise, w_ih0, w_hh0, b_ih0, b_hh0,
        w_ih1, w_hh1, b_ih1, b_hh1,
        w_ih2, w_hh2, b_ih2, b_hh2,
        fc1w, fc1b, fc2w, fc2b, fc3w, fc3b,
        flp, (float*)d_out);
}

// Round 12
// 808.349 us; speedup vs baseline: 3.1908x; 1.1762x over previous
//
#include <hip/hip_runtime.h>

#define NT 512   // 8 waves; wave w owns gate-tiles {2w,2w+1} = units 8w..8w+7 (all 4 gates)

typedef _Float16 f16x8 __attribute__((ext_vector_type(8)));
typedef _Float16 f16x4 __attribute__((ext_vector_type(4)));
typedef float    f32x4 __attribute__((ext_vector_type(4)));

#define MFMA(a, b, c) __builtin_amdgcn_mfma_f32_16x16x32_f16((a), (b), (c), 0, 0, 0)

#if __has_builtin(__builtin_amdgcn_exp2f)
__device__ __forceinline__ float fexp(float x) { return __builtin_amdgcn_exp2f(x * 1.4426950408889634f); }
#else
__device__ __forceinline__ float fexp(float x) { return __expf(x); }
#endif
#if __has_builtin(__builtin_amdgcn_rcpf)
__device__ __forceinline__ float frcp(float x) { return __builtin_amdgcn_rcpf(x); }
#else
__device__ __forceinline__ float frcp(float x) { return 1.0f / x; }
#endif
__device__ __forceinline__ float sigm(float x)  { return frcp(1.0f + fexp(-x)); }
__device__ __forceinline__ float tanh_(float x) { return 1.0f - 2.0f * frcp(1.0f + fexp(2.0f * x)); }
__device__ __forceinline__ float lrelu(float x) { return x > 0.0f ? x : 0.01f * x; }

__device__ __forceinline__ f16x8 ld8(const float* p) {
    const float4* q = (const float4*)p;
    float4 a = q[0], b = q[1];
    f16x8 r = { (_Float16)a.x, (_Float16)a.y, (_Float16)a.z, (_Float16)a.w,
                (_Float16)b.x, (_Float16)b.y, (_Float16)b.z, (_Float16)b.w };
    return r;
}

__global__ __launch_bounds__(NT, 2)
void gen_kernel(
    const float* __restrict__ noise,
    const float* __restrict__ w_ih0, const float* __restrict__ w_hh0,
    const float* __restrict__ b_ih0, const float* __restrict__ b_hh0,
    const float* __restrict__ w_ih1, const float* __restrict__ w_hh1,
    const float* __restrict__ b_ih1, const float* __restrict__ b_hh1,
    const float* __restrict__ w_ih2, const float* __restrict__ w_hh2,
    const float* __restrict__ b_ih2, const float* __restrict__ b_hh2,
    const float* __restrict__ fc1_w, const float* __restrict__ fc1_b,
    const float* __restrict__ fc2_w, const float* __restrict__ fc2_b,
    const float* __restrict__ fc3_w, const float* __restrict__ fc3_b,
    const int*   __restrict__ flow_len_p,
    float* __restrict__ out)
{
    // h-state, rotated banking (R11): k-group kg of col c stored at slot (kg+c)&7.
    // Cols 8-15 are dead samples: zero-initialized and NEVER written (repack).
    __shared__ _Float16 sh[3][2][16 * 64] __attribute__((aligned(16)));  // 12 KB
    __shared__ _Float16 sx [16][40] __attribute__((aligned(16)));
    __shared__ _Float16 sy1[16][40] __attribute__((aligned(16)));
    __shared__ _Float16 sy2[16][40] __attribute__((aligned(16)));

    const int tid  = threadIdx.x;
    const int l    = tid & 63;
    const int w    = tid >> 6;     // wave 0..7
    const int ls   = l & 15;       // sample col (B/C) == row-in-tile (A)
    const int lj   = l >> 4;       // k-group / C row-group
    const int base = blockIdx.x * 8;
    const int T    = flow_len_p[0];

    // ---------- A fragments ----------
    const int gA  = ls & 3;
    const int rA0 = gA * 64 + 4 * (2 * w + 0) + (ls >> 2);
    const int rA1 = gA * 64 + 4 * (2 * w + 1) + (ls >> 2);

    f16x8 A1[2][4], A2[2][4], A0[2][3];
#pragma unroll
    for (int kc = 0; kc < 2; ++kc) {
        A1[0][kc]     = ld8(w_ih1 + rA0 * 64 + 32 * kc + 8 * lj);
        A1[1][kc]     = ld8(w_ih1 + rA1 * 64 + 32 * kc + 8 * lj);
        A1[0][2 + kc] = ld8(w_hh1 + rA0 * 64 + 32 * kc + 8 * lj);
        A1[1][2 + kc] = ld8(w_hh1 + rA1 * 64 + 32 * kc + 8 * lj);
        A2[0][kc]     = ld8(w_ih2 + rA0 * 64 + 32 * kc + 8 * lj);
        A2[1][kc]     = ld8(w_ih2 + rA1 * 64 + 32 * kc + 8 * lj);
        A2[0][2 + kc] = ld8(w_hh2 + rA0 * 64 + 32 * kc + 8 * lj);
        A2[1][2 + kc] = ld8(w_hh2 + rA1 * 64 + 32 * kc + 8 * lj);
        A0[0][kc]     = ld8(w_hh0 + rA0 * 64 + 32 * kc + 8 * lj);
        A0[1][kc]     = ld8(w_hh0 + rA1 * 64 + 32 * kc + 8 * lj);
    }
#pragma unroll
    for (int tt = 0; tt < 2; ++tt) {
        const int r = tt ? rA1 : rA0;
        f16x8 v;
#pragma unroll
        for (int i = 0; i < 8; ++i) {
            int kl = 8 * lj + i;
            float x = (kl < 3) ? w_ih0[r * 3 + kl]
                    : (kl == 3) ? (b_ih0[r] + b_hh0[r]) : 0.0f;
            v[i] = (_Float16)x;
        }
        A0[tt][2] = v;
    }
    // head A-frags (wave 0 uses them; cheap to load everywhere)
    f16x8 F1[2][2], F2, F3;
#pragma unroll
    for (int tt = 0; tt < 2; ++tt)
#pragma unroll
        for (int kc = 0; kc < 2; ++kc)
            F1[tt][kc] = ld8(fc1_w + (16 * tt + ls) * 64 + 32 * kc + 8 * lj);
    F2 = ld8(fc2_w + ls * 32 + 8 * lj);
    {
        f16x8 v;
#pragma unroll
        for (int i = 0; i < 8; ++i) {
            int k = 8 * lj + i;
            v[i] = (_Float16)((ls < 3 && k < 16) ? fc3_w[ls * 16 + k] : 0.0f);
        }
        F3 = v;
    }
    // per-lane live cell after repack: unit u_own, col cs
    const int uc0 = 8 * w + lj, uc1 = 8 * w + 4 + lj;
    const int u_own = (ls < 8) ? uc0 : uc1;
    const int cs    = ls & 7;
    const int whaddr = cs * 64 + 8 * (((u_own >> 3) + cs) & 7) + (u_own & 7);
    float b1o[4], b2o[4];
#pragma unroll
    for (int g = 0; g < 4; ++g) {
        b1o[g] = b_ih1[g * 64 + u_own] + b_hh1[g * 64 + u_own];
        b2o[g] = b_ih2[g * 64 + u_own] + b_hh2[g * 64 + u_own];
    }
    float hb1a[4], hb1b[4], hb2[4];
#pragma unroll
    for (int r = 0; r < 4; ++r) {
        hb1a[r] = fc1_b[4 * lj + r];
        hb1b[r] = fc1_b[16 + 4 * lj + r];
        hb2[r]  = fc2_b[4 * lj + r];
    }
    float fb3[3] = { fc3_b[0], fc3_b[1], fc3_b[2] };

    // ---------- LDS init ----------
    for (int i = tid; i < 3 * 2 * 16 * 64; i += NT) ((_Float16*)sh)[i] = (_Float16)0.0f;
    for (int i = tid; i < 16 * 40; i += NT) {
        ((_Float16*)sx)[i]  = (_Float16)0.0f;
        ((_Float16*)sy1)[i] = (_Float16)0.0f;
        ((_Float16*)sy2)[i] = (_Float16)0.0f;
    }
    __syncthreads();
    if (tid < 16) sx[tid][3] = (_Float16)1.0f;
    if (tid < 24) {
        int s = tid / 3, d = tid % 3;
        sx[s][d] = (_Float16)noise[(base + s) * 3 + d];
    }

    float c0s = 0.0f, c1s = 0.0f, c2s = 0.0f;
    const float zb[4] = {0, 0, 0, 0};
    __syncthreads();

#define RD(L, p, kg) (*(const f16x8*)&sh[L][p][ls * 64 + 8 * (((kg) + ls) & 7)])

    // repack: lane ls<8 keeps a0's cell; lane ls>=8 takes partner's a1 cell
#define REPACK(cell, a0, a1)                                                   \
    float cell[4];                                                             \
    _Pragma("unroll")                                                          \
    for (int r = 0; r < 4; ++r) {                                              \
        float v_ = __shfl_xor(a1[r], 8);                                       \
        cell[r] = (ls < 8) ? a0[r] : v_;                                       \
    }

#define ACTC(cell, bo, cref, L, p) {                                           \
        float gi = cell[0] + bo[0], gf = cell[1] + bo[1];                      \
        float gg = cell[2] + bo[2], go = cell[3] + bo[3];                      \
        cref = sigm(gf) * cref + sigm(gi) * tanh_(gg);                         \
        sh[L][p][whaddr] = (_Float16)(sigm(go) * tanh_(cref)); }

    // ---------- prologue: h0(0) from noise ----------
    {
        f16x8 bx = *(const f16x8*)&sx[ls][8 * lj];
        f32x4 a0 = {0, 0, 0, 0}, a1 = {0, 0, 0, 0};
        a0 = MFMA(A0[0][2], bx, a0);
        a1 = MFMA(A0[1][2], bx, a1);
        REPACK(cell, a0, a1)
        ACTC(cell, zb, c0s, 0, 0)
    }
    __syncthreads();
    // preload h1(buf1)=zeros for first I1
    f16x8 ph1a = RD(1, 1, lj), ph1b = RD(1, 1, 4 + lj);

    // ---------- time loop: 4 barriers/step ----------
    for (int t = 0; t < T; ++t) {
        const int pc = t & 1, pp = pc ^ 1;
        // I1: gates1 = [Wi1|Wh1]·[h0(pc); h1(pp)] -> ACT1 -> h1(pc)
        f16x8 r0 = RD(0, pc, lj), r1 = RD(0, pc, 4 + lj);
        f16x8 nh2a = RD(2, pp, lj), nh2b = RD(2, pp, 4 + lj);   // hoist for I2
        {
            f32x4 a0 = {0, 0, 0, 0}, a1 = {0, 0, 0, 0};
            a0 = MFMA(A1[0][0], r0, a0);   a1 = MFMA(A1[1][0], r0, a1);
            a0 = MFMA(A1[0][1], r1, a0);   a1 = MFMA(A1[1][1], r1, a1);
            a0 = MFMA(A1[0][2], ph1a, a0); a1 = MFMA(A1[1][2], ph1a, a1);
            a0 = MFMA(A1[0][3], ph1b, a0); a1 = MFMA(A1[1][3], ph1b, a1);
            REPACK(cell, a0, a1)
            ACTC(cell, b1o, c1s, 1, pc)
        }
        __syncthreads();
        // I2: gates2 = [Wi2|Wh2]·[h1(pc); h2(pp)] -> ACT2 -> h2(pc)
        {
            f16x8 s0 = RD(1, pc, lj), s1 = RD(1, pc, 4 + lj);
            f32x4 a0 = {0, 0, 0, 0}, a1 = {0, 0, 0, 0};
            a0 = MFMA(A2[0][0], s0, a0);   a1 = MFMA(A2[1][0], s0, a1);
            a0 = MFMA(A2[0][1], s1, a0);   a1 = MFMA(A2[1][1], s1, a1);
            a0 = MFMA(A2[0][2], nh2a, a0); a1 = MFMA(A2[1][2], nh2a, a1);
            a0 = MFMA(A2[0][3], nh2b, a0); a1 = MFMA(A2[1][3], nh2b, a1);
            REPACK(cell, a0, a1)
            ACTC(cell, b2o, c2s, 2, pc)
        }
        __syncthreads();
        // I3: layer0-hh from register-held r0,r1 (acc to I4)  ||  head on wave 0
        f32x4 h0a = {0, 0, 0, 0}, h0b = {0, 0, 0, 0};
        h0a = MFMA(A0[0][0], r0, h0a); h0b = MFMA(A0[1][0], r0, h0b);
        h0a = MFMA(A0[0][1], r1, h0a); h0b = MFMA(A0[1][1], r1, h0b);
        if (w == 0) {
            f16x8 bh0 = RD(2, pc, lj), bh1 = RD(2, pc, 4 + lj);
            f32x4 y1a = {0, 0, 0, 0}, y1b = {0, 0, 0, 0};
            y1a = MFMA(F1[0][0], bh0, y1a); y1b = MFMA(F1[1][0], bh0, y1b);
            y1a = MFMA(F1[0][1], bh1, y1a); y1b = MFMA(F1[1][1], bh1, y1b);
            f16x4 v;
#pragma unroll
            for (int r = 0; r < 4; ++r) v[r] = (_Float16)lrelu(y1a[r] + hb1a[r]);
            *(f16x4*)&sy1[ls][4 * lj] = v;
#pragma unroll
            for (int r = 0; r < 4; ++r) v[r] = (_Float16)lrelu(y1b[r] + hb1b[r]);
            *(f16x4*)&sy1[ls][16 + 4 * lj] = v;
            f16x8 by1 = *(const f16x8*)&sy1[ls][8 * lj];
            f32x4 y2 = {0, 0, 0, 0};
            y2 = MFMA(F2, by1, y2);
#pragma unroll
            for (int r = 0; r < 4; ++r) v[r] = (_Float16)lrelu(y2[r] + hb2[r]);
            *(f16x4*)&sy2[ls][4 * lj] = v;
            f16x8 by2 = *(const f16x8*)&sy2[ls][8 * lj];
            f32x4 y3 = {0, 0, 0, 0};
            y3 = MFMA(F3, by2, y3);
            if (lj == 0) {
                float o0 = lrelu(y3[0] + fb3[0]);
                float o1 = lrelu(y3[1] + fb3[1]);
                float o2 = lrelu(y3[2] + fb3[2]);
                sx[ls][0] = (_Float16)o0;
                sx[ls][1] = (_Float16)o1;
                sx[ls][2] = (_Float16)o2;
                if (ls < 8) {
                    float* op = out + ((size_t)(base + ls) * T + t) * 3;
                    op[0] = o0; op[1] = o1; op[2] = o2;
                }
            }
        }
        __syncthreads();
        // I4: gates0 += Wi0p·[y3;1;0..] -> ACT0 -> h0(pp)
        {
            f16x8 bx = *(const f16x8*)&sx[ls][8 * lj];
            h0a = MFMA(A0[0][2], bx, h0a);
            h0b = MFMA(A0[1][2], bx, h0b);
            REPACK(cell, h0a, h0b)
            ACTC(cell, zb, c0s, 0, pp)
        }
        ph1a = RD(1, pc, lj); ph1b = RD(1, pc, 4 + lj);  // hoist for next I1
        __syncthreads();
    }
}

extern "C" void kernel_launch(void* const* d_in, const int* in_sizes, int n_in,
                              void* d_out, int out_size, void* d_ws, size_t ws_size,
                              hipStream_t stream) {
    const float* noise = (const float*)d_in[0];
    const float* w_ih0 = (const float*)d_in[1];
    const float* w_hh0 = (const float*)d_in[2];
    const float* b_ih0 = (const float*)d_in[3];
    const float* b_hh0 = (const float*)d_in[4];
    const float* w_ih1 = (const float*)d_in[5];
    const float* w_hh1 = (const float*)d_in[6];
    const float* b_ih1 = (const float*)d_in[7];
    const float* b_hh1 = (const float*)d_in[8];
    const float* w_ih2 = (const float*)d_in[9];
    const float* w_hh2 = (const float*)d_in[10];
    const float* b_ih2 = (const float*)d_in[11];
    const float* b_hh2 = (const float*)d_in[12];
    const float* fc1w  = (const float*)d_in[13];
    const float* fc1b  = (const float*)d_in[14];
    const float* fc2w  = (const float*)d_in[15];
    const float* fc2b  = (const float*)d_in[16];
    const float* fc3w  = (const float*)d_in[17];
    const float* fc3b  = (const float*)d_in[18];
    const int*   flp   = (const int*)d_in[19];

    gen_kernel<<<dim3(256), dim3(NT), 0, stream>>>(
        noise, w_ih0, w_hh0, b_ih0, b_hh0,
        w_ih1, w_hh1, b_ih1, b_hh1,
        w_ih2, w_hh2, b_ih2, b_hh2,
        fc1w, fc1b, fc2w, fc2b, fc3w, fc3b,
        flp, (float*)d_out);
}